// Round 14
// baseline (205.931 us; speedup 1.0000x reference)
//
#include <hip/hip_runtime.h>
#include <math.h>

#define BN_EPS 1e-5f

typedef short bf16x8 __attribute__((ext_vector_type(8)));
typedef float f32x4 __attribute__((ext_vector_type(4)));
typedef float f32x16 __attribute__((ext_vector_type(16)));
typedef unsigned short ushort8v __attribute__((ext_vector_type(8)));
typedef unsigned int uint;
typedef unsigned short ushort;

__device__ inline ushort f2bf(float f) {           // RNE float->bf16
    uint u = __float_as_uint(f);
    uint r = u + 0x7FFFu + ((u >> 16) & 1u);
    return (ushort)(r >> 16);
}
__device__ inline float bf2f(ushort u) { return __uint_as_float(((uint)u) << 16); }
__device__ inline uint cvtpk(float lo, float hi) { // packed 2xbf16 (RNE)
    uint r;
    asm("v_cvt_pk_bf16_f32 %0, %1, %2" : "=v"(r) : "v"(lo), "v"(hi));
    return r;
}

// ---------------------------------------------------------------------------
// Per-channel scale/shift for both BN layers: y = acc*sc + sh, then ReLU.
// ---------------------------------------------------------------------------
__global__ void scsh_kernel(const float* b1, const float* g1, const float* bb1,
                            const float* m1, const float* v1,
                            const float* b2, const float* g2, const float* bb2,
                            const float* m2, const float* v2,
                            float* scsh1, float* scsh2) {
    int t = threadIdx.x;
    if (t < 128) {
        float sc = g1[t] * rsqrtf(v1[t] + BN_EPS);
        scsh1[t] = sc;
        scsh1[128 + t] = (b1[t] - m1[t]) * sc + bb1[t];
    } else {
        int c = t - 128;
        float sc = g2[c] * rsqrtf(v2[c] + BN_EPS);
        scsh2[c] = sc;
        scsh2[128 + c] = (b2[c] - m2[c]) * sc + bb2[c];
    }
}

// ---------------------------------------------------------------------------
// x fp32 NCHW [16][64][128][128] -> xT bf16 16ci-planar [b][h][cc4][w][16]
// + fused pool partial sums (atomicAdd raw sums into pooled1).
// ---------------------------------------------------------------------------
__global__ void xprep_kernel(const float* __restrict__ x, ushort* __restrict__ xT,
                             float* __restrict__ pooled1) {
    __shared__ float t[64][65];
    const int b = blockIdx.y;
    const int p0 = blockIdx.x * 64;
    const int tid = threadIdx.x;
#pragma unroll
    for (int it = 0; it < 16; ++it) {
        const int idx = it * 256 + tid;
        const int ci = idx >> 6, p = idx & 63;
        t[ci][p] = x[((size_t)b * 64 + ci) * 16384 + p0 + p];
    }
    __syncthreads();
    const int h = p0 >> 7;
#pragma unroll
    for (int it = 0; it < 2; ++it) {
        const int p = it * 32 + (tid >> 3);
        const int w = (p0 & 127) + p;
        const int c0 = (tid & 7) * 8;
        const int cc = c0 >> 4;
        ushort8v u;
#pragma unroll
        for (int j = 0; j < 8; ++j) u[j] = f2bf(t[c0 + j][p]);
        *(ushort8v*)&xT[(((size_t)(b * 128 + h) * 4 + cc) * 128 + w) * 16 + (c0 & 15)] = u;
    }
    if (tid < 64) {
        float s = 0.f;
#pragma unroll 8
        for (int p = 0; p < 64; ++p) s += t[tid][p];
        atomicAdd(&pooled1[b * 64 + tid], s);
    }
}

// ---------------------------------------------------------------------------
// Pool hT (bf16 16ci-planar [b][h][cc8][w][16]) -> pooled2 raw sums (atomic).
// ---------------------------------------------------------------------------
__global__ void pool2h_kernel(const ushort* __restrict__ hT, float* __restrict__ pooled2) {
    const int b = blockIdx.x, slab = blockIdx.y;
    const int tid = threadIdx.x;                  // 256
    const int cc = tid >> 5, o = (tid >> 4) & 1, wb = tid & 15;
    float a[8] = {0.f, 0.f, 0.f, 0.f, 0.f, 0.f, 0.f, 0.f};
    for (int r = 0; r < 4; ++r) {
        const int h = slab * 4 + r;
        const ushort* base = hT + ((size_t)(b * 128 + h) * 8 + cc) * 2048 + o * 8;
#pragma unroll
        for (int k = 0; k < 8; ++k) {
            const ushort8v u = *(const ushort8v*)(base + (wb + k * 16) * 16);
#pragma unroll
            for (int j = 0; j < 8; ++j) a[j] += bf2f(u[j]);
        }
    }
    __shared__ float sp[16][8][17];
    const int grp0 = cc * 2 + o;
#pragma unroll
    for (int j = 0; j < 8; ++j) sp[grp0][j][wb] = a[j];
    __syncthreads();
    if (tid < 128) {
        const int grp = tid >> 3, j = tid & 7;
        float s = 0.f;
#pragma unroll
        for (int k = 0; k < 16; ++k) s += sp[grp][j][k];
        const int c = (grp >> 1) * 16 + (grp & 1) * 8 + j;
        atomicAdd(&pooled2[b * 128 + c], s);
    }
}

// ---------------------------------------------------------------------------
// Routing (from raw pooled sums) + expert mix, writing wmix as the conv
// kernel's LDS weight image: per (b,cc16): 2304 granules of 16B,
// granule = tap*256 + oct*128 + co  (LINEAR), elems = 8 ci.
// ---------------------------------------------------------------------------
template <int CIN>
__global__ void mix_route_kernel(const float* __restrict__ w, const float* __restrict__ pooled,
                                 const float* __restrict__ fcw, const float* __restrict__ fcb,
                                 ushort* __restrict__ wmix) {
    constexpr int NCC = CIN / 16;
    __shared__ float rwl[48];
    const int tid = threadIdx.x;
    if (tid < 48) {
        const int bb = tid / 3, e = tid % 3;
        float d = 0.f;
        for (int c = 0; c < CIN; ++c) d += pooled[bb * CIN + c] * fcw[e * CIN + c];
        const float s = fcb[e] + d * (1.f / 16384.f);
        rwl[tid] = 1.f / (1.f + expf(-s));
    }
    __syncthreads();
    const int co = blockIdx.x;           // 0..127
    for (int b = 0; b < 16; ++b) {
        const float r0 = rwl[b * 3 + 0], r1 = rwl[b * 3 + 1], r2 = rwl[b * 3 + 2];
        for (int idx = tid; idx < CIN * 9; idx += 256) {
            const int ci = idx & (CIN - 1);
            const int tap = idx / CIN;
            const size_t off = ((size_t)co * CIN + ci) * 9 + tap;
            const float m = r0 * w[off]
                          + r1 * w[off + (size_t)128 * CIN * 9]
                          + r2 * w[off + (size_t)2 * 128 * CIN * 9];
            const int cc = ci >> 4, o = (ci >> 3) & 1, e = ci & 7;
            const size_t dst = ((size_t)(b * NCC + cc) * 2304
                             + tap * 256 + o * 128 + co) * 8 + e;
            wmix[dst] = f2bf(m);
        }
    }
}

// ---------------------------------------------------------------------------
// MFMA implicit-GEMM conv3x3(pad1) + fused bias/BN/ReLU. v14 (= v13 + T4):
//  - v13 base: 16 waves (4/SIMD), wave tile 64co x (2rows x 32px), rolling
//    B-frags (30 ds_reads/wave/chunk), linear LDS layouts, base+imm reads
//  - NEW SCHEDULE (T4 counted vmcnt, T5 setprio): every wave issues EXACTLY
//    4 global_load_lds per stage (rebalanced slots + dummy loads to a 1KB
//    trash slot); per chunk:
//      stage4(next) -> s_waitcnt vmcnt(4) -> raw s_barrier (NO vmcnt-0 drain)
//      -> setprio(1) taps setprio(0) -> raw s_barrier
//    Loads now stay in flight across barriers; the vmcnt(0) pipeline collapse
//    that capped MfmaUtil at ~40% across R6-R13 is removed.
// ---------------------------------------------------------------------------
template <int CIN, bool TO_BF16>
__global__ __launch_bounds__(1024, 4)
void conv_mfma12_kernel(const ushort* __restrict__ xT, const ushort* __restrict__ wmix,
                        const float* __restrict__ scsh,
                        float* __restrict__ outf, ushort* __restrict__ outh) {
    constexpr int NCC = CIN / 16;
    constexpr int IBUF = 24960;          // 6 rows * 260 granules * 16B
    constexpr int WOFF = 2 * IBUF;       // 49920
    constexpr int WBUF = 36864;          // 2304 granules * 16B
    constexpr int TRASH = 2 * IBUF + 2 * WBUF;   // 123648
    __shared__ __align__(16) char smem[123648 + 1024];

    const int L = ((blockIdx.x & 7) << 6) | (blockIdx.x >> 3);  // 64 per XCD
    const int b = L >> 5;
    const int rt = L & 31;               // output rows rt*4 .. rt*4+3

    const int tid = threadIdx.x;
    const int lane = tid & 63, wid = tid >> 6;   // 16 waves
    const int wm = wid >> 3;                     // 0..1 co-half
    const int rp = (wid >> 2) & 1;               // 0..1 row-pair
    const int cb = wid & 3;                      // 0..3 col-block (32 px)
    const int l31 = lane & 31, lhi = lane >> 5;

    f32x16 acc[2][2];                            // [mf][nf=row-in-pair]
#pragma unroll
    for (int i = 0; i < 2; ++i)
#pragma unroll
        for (int j = 0; j < 2; ++j)
#pragma unroll
            for (int r = 0; r < 16; ++r) acc[i][j][r] = 0.f;

    const ushort* inb = xT + (size_t)b * 128 * NCC * 2048;
    const ushort* wmb = wmix + (size_t)b * NCC * 18432;

    // ---- hoisted staging state: EXACTLY 4 gllds per wave per stage ----
    // I slots: slot wid (r=ir0) all waves; slot wid+16 (r=ir0+4) for wid<8.
    const int ihalf = wid & 1, ioct = (wid >> 1) & 1, ir0 = (wid & 15) >> 2;
    const int iv = (ihalf * 64 + lane) * 16 + ioct * 8;   // ushort off in (row,cc)
    const int idst0 = (ir0 * 260 + ioct * 130 + 1 + ihalf * 64) * 16;
    const int hg0 = rt * 4 - 1 + ir0;
    const bool ok0 = (unsigned)hg0 < 128u;                // rows 0..3 of tile
    const bool ok4 = (unsigned)(hg0 + 4) < 128u;          // rows 4..5 (wid<8)
    // W slots: all waves {2wid, 2wid+1}; wid 8..11 extra {24+wid}; wid12-15 dummy.
    const int wkA = 2 * wid, wkB = 2 * wid + 1;
    const int wkC = 24 + wid;                             // 32..35 for wid 8..11
    char* const trash = smem + TRASH;

    auto stage4 = [&](char* dI, char* dW, int cc) {
        const size_t ccI = (size_t)cc * 2048;
        // I #1 (all waves)
        {
            const ushort* src = inb + (ok0 ? (size_t)hg0 * (NCC * 2048) : 0) + ccI + iv;
            void* dst = ok0 ? (void*)(dI + idst0) : (void*)trash;
            __builtin_amdgcn_global_load_lds(
                (const __attribute__((address_space(1))) void*)src,
                (__attribute__((address_space(3))) void*)dst, 16, 0, 0);
        }
        const ushort* ws = wmb + (size_t)cc * 18432;
        // W #1, #2 (all waves)
        __builtin_amdgcn_global_load_lds(
            (const __attribute__((address_space(1))) void*)(ws + wkA * 512 + lane * 8),
            (__attribute__((address_space(3))) void*)(dW + wkA * 1024), 16, 0, 0);
        __builtin_amdgcn_global_load_lds(
            (const __attribute__((address_space(1))) void*)(ws + wkB * 512 + lane * 8),
            (__attribute__((address_space(3))) void*)(dW + wkB * 1024), 16, 0, 0);
        // 4th load: wid<8 -> I #2 ; wid 8..11 -> W #3 ; wid 12..15 -> dummy
        if (wid < 8) {
            const ushort* src = inb + (ok4 ? (size_t)(hg0 + 4) * (NCC * 2048) : 0) + ccI + iv;
            void* dst = ok4 ? (void*)(dI + idst0 + 4 * 4160) : (void*)trash;
            __builtin_amdgcn_global_load_lds(
                (const __attribute__((address_space(1))) void*)src,
                (__attribute__((address_space(3))) void*)dst, 16, 0, 0);
        } else if (wid < 12) {
            __builtin_amdgcn_global_load_lds(
                (const __attribute__((address_space(1))) void*)(ws + wkC * 512 + lane * 8),
                (__attribute__((address_space(3))) void*)(dW + wkC * 1024), 16, 0, 0);
        } else {
            __builtin_amdgcn_global_load_lds(
                (const __attribute__((address_space(1))) void*)(ws + lane * 8),
                (__attribute__((address_space(3))) void*)trash, 16, 0, 0);
        }
    };

    // per-lane read bases. B: tile-local row (rp*2 + dy + nf), colp = cb*32+dx+l31
    // (halo at colp 0 => no +1). A: granule tap*256 + lhi*128 + wm*64+mf*32+l31.
    const int ibase = (rp * 2 * 260 + lhi * 130 + cb * 32 + l31) * 16;
    const int wbase = (lhi * 128 + wm * 64 + l31) * 16;
    const char* pI0 = smem + ibase;
    const char* pI1 = smem + IBUF + ibase;
    const char* pW0 = smem + WOFF + wbase;
    const char* pW1 = smem + WOFF + WBUF + wbase;

    auto taps = [&](const char* pI, const char* pW) {
        bf16x8 rb0[3], rb1[3];                   // rows (rp*2+dy), (rp*2+dy+1)
#pragma unroll
        for (int dx = 0; dx < 3; ++dx) {
            rb0[dx] = *(const bf16x8*)(pI + (0 * 260 + dx) * 16);
            rb1[dx] = *(const bf16x8*)(pI + (1 * 260 + dx) * 16);
        }
#pragma unroll
        for (int dy = 0; dy < 3; ++dy) {
#pragma unroll
            for (int dx = 0; dx < 3; ++dx) {
                const int tap = dy * 3 + dx;
                const bf16x8 af0 = *(const bf16x8*)(pW + (tap * 256) * 16);
                const bf16x8 af1 = *(const bf16x8*)(pW + (tap * 256 + 32) * 16);
                acc[0][0] = __builtin_amdgcn_mfma_f32_32x32x16_bf16(af0, rb0[dx], acc[0][0], 0, 0, 0);
                acc[1][0] = __builtin_amdgcn_mfma_f32_32x32x16_bf16(af1, rb0[dx], acc[1][0], 0, 0, 0);
                acc[0][1] = __builtin_amdgcn_mfma_f32_32x32x16_bf16(af0, rb1[dx], acc[0][1], 0, 0, 0);
                acc[1][1] = __builtin_amdgcn_mfma_f32_32x32x16_bf16(af1, rb1[dx], acc[1][1], 0, 0, 0);
            }
            if (dy < 2) {
#pragma unroll
                for (int dx = 0; dx < 3; ++dx) {
                    rb0[dx] = rb1[dx];
                    rb1[dx] = *(const bf16x8*)(pI + ((dy + 2) * 260 + dx) * 16);
                }
            }
        }
    };

    // ---- one-time zeroing: halo cols (colp 0,129 per row/oct), both bufs ----
    if (tid < 48) {
        const int bi = tid >= 24, idx = tid - bi * 24;
        const int r = idx >> 2, j = idx & 3;
        const int g = r * 260 + (j >> 1) * 130 + (j & 1) * 129;
        *(f32x4*)(smem + bi * IBUF + g * 16) = f32x4{0.f, 0.f, 0.f, 0.f};
    }
    if (rt == 0 || rt == 31) {           // OOB image rows (r=0 or r=5)
        const int r = (rt == 0) ? 0 : 5;
        if (tid < 520) {
            const int bi = tid >= 260, gr = tid - bi * 260;
            *(f32x4*)(smem + bi * IBUF + (r * 260 + gr) * 16) = f32x4{0.f, 0.f, 0.f, 0.f};
        }
    }

    stage4(smem, smem + WOFF, 0);
    asm volatile("s_waitcnt vmcnt(0) lgkmcnt(0)" ::: "memory");
    __builtin_amdgcn_s_barrier();        // stage(0) + zeroes visible

#pragma unroll
    for (int cc = 0; cc < NCC; cc += 2) {
        // ---- chunk cc (buffers 0) ----
        stage4(smem + IBUF, smem + WOFF + WBUF, cc + 1);
        asm volatile("s_waitcnt vmcnt(4)" ::: "memory");   // chunk cc landed
        __builtin_amdgcn_sched_barrier(0);
        __builtin_amdgcn_s_barrier();
        __builtin_amdgcn_s_setprio(1);
        taps(pI0, pW0);
        __builtin_amdgcn_s_setprio(0);
        __builtin_amdgcn_s_barrier();

        // ---- chunk cc+1 (buffers 1) ----
        if (cc + 2 < NCC) {
            stage4(smem, smem + WOFF, cc + 2);
            asm volatile("s_waitcnt vmcnt(4)" ::: "memory"); // chunk cc+1 landed
        } else {
            asm volatile("s_waitcnt vmcnt(0)" ::: "memory"); // drain final stage
        }
        __builtin_amdgcn_sched_barrier(0);
        __builtin_amdgcn_s_barrier();
        __builtin_amdgcn_s_setprio(1);
        taps(pI1, pW1);
        __builtin_amdgcn_s_setprio(0);
        __builtin_amdgcn_s_barrier();
    }
    __builtin_amdgcn_sched_barrier(0);

    // ---- epilogue: y = relu(acc*sc + sh) ----
    if constexpr (!TO_BF16) {
        // fp32 NCHW direct: each (mf,q,s,nf) = 32 consecutive floats of a row
#pragma unroll
        for (int mf = 0; mf < 2; ++mf) {
            const int cob = wm * 64 + mf * 32 + 4 * lhi;
            f32x4 sc[4], sh[4];
#pragma unroll
            for (int q = 0; q < 4; ++q) {
                sc[q] = *(const f32x4*)&scsh[cob + 8 * q];
                sh[q] = *(const f32x4*)&scsh[128 + cob + 8 * q];
            }
#pragma unroll
            for (int nf = 0; nf < 2; ++nf) {
                const size_t pbase = (size_t)(rt * 4 + rp * 2 + nf) * 128 + cb * 32 + l31;
#pragma unroll
                for (int q = 0; q < 4; ++q)
#pragma unroll
                    for (int s = 0; s < 4; ++s) {
                        float y = fmaf(acc[mf][nf][q * 4 + s], sc[q][s], sh[q][s]);
                        y = y > 0.f ? y : 0.f;
                        outf[((size_t)(b * 128 + cob + 8 * q + s)) * 16384 + pbase] = y;
                    }
            }
        }
    } else {
        // bf16 16ci-planar hT via padded-LDS transpose, 2 passes of 2 rows
        ushort* sf = (ushort*)smem;                      // [256 px][136]
#pragma unroll
        for (int p = 0; p < 2; ++p) {
            if (rp == p) {
#pragma unroll
                for (int mf = 0; mf < 2; ++mf)
#pragma unroll
                    for (int q = 0; q < 4; ++q) {
                        const int co4 = wm * 64 + mf * 32 + 8 * q + 4 * lhi;
                        const f32x4 sc = *(const f32x4*)&scsh[co4];
                        const f32x4 sh = *(const f32x4*)&scsh[128 + co4];
#pragma unroll
                        for (int nf = 0; nf < 2; ++nf) {
                            const int px = nf * 128 + cb * 32 + l31;
                            float v[4];
#pragma unroll
                            for (int s = 0; s < 4; ++s) {
                                float y = fmaf(acc[mf][nf][q * 4 + s], sc[s], sh[s]);
                                v[s] = y > 0.f ? y : 0.f;
                            }
                            uint2 pk;
                            pk.x = cvtpk(v[0], v[1]);
                            pk.y = cvtpk(v[2], v[3]);
                            *(uint2*)&sf[px * 136 + co4] = pk;
                        }
                    }
            }
            __syncthreads();
#pragma unroll
            for (int it = 0; it < 2; ++it) {
                const int id = it * 1024 + tid;          // [lr2][cc8][w128]
                const int lr = id >> 10, cc = (id >> 7) & 7, w = id & 127;
                const uint4 v0 = *(const uint4*)&sf[(lr * 128 + w) * 136 + cc * 16];
                const uint4 v1 = *(const uint4*)&sf[(lr * 128 + w) * 136 + cc * 16 + 8];
                ushort* dst = outh + (((size_t)(b * 128 + rt * 4 + 2 * p + lr)) * 8 + cc) * 2048 + w * 16;
                *(uint4*)dst = v0;
                *(uint4*)(dst + 8) = v1;
            }
            if (p == 0) __syncthreads();
        }
    }
}

// ---------------------------------------------------------------------------
extern "C" void kernel_launch(void* const* d_in, const int* in_sizes, int n_in,
                              void* d_out, int out_size, void* d_ws, size_t ws_size,
                              hipStream_t stream) {
    const float* x     = (const float*)d_in[0];
    const float* w1    = (const float*)d_in[1];
    const float* b1    = (const float*)d_in[2];
    const float* fc1_w = (const float*)d_in[3];
    const float* fc1_b = (const float*)d_in[4];
    const float* bn1g  = (const float*)d_in[5];
    const float* bn1b  = (const float*)d_in[6];
    const float* bn1m  = (const float*)d_in[7];
    const float* bn1v  = (const float*)d_in[8];
    const float* w2    = (const float*)d_in[9];
    const float* b2    = (const float*)d_in[10];
    const float* fc2_w = (const float*)d_in[11];
    const float* fc2_b = (const float*)d_in[12];
    const float* bn2g  = (const float*)d_in[13];
    const float* bn2b  = (const float*)d_in[14];
    const float* bn2m  = (const float*)d_in[15];
    const float* bn2v  = (const float*)d_in[16];

    float* out = (float*)d_out;
    char* ws = (char*)d_ws;

    // workspace layout (bytes)
    ushort* hT    = (ushort*)(ws + 0);            //  67,108,864
    ushort* xT    = (ushort*)(ws + 67108864);     //  33,554,432
    ushort* wmix1 = (ushort*)(ws + 100663296);    //   2,359,296
    ushort* wmix2 = (ushort*)(ws + 103022592);    //   4,718,592
    float*  pool1 = (float*) (ws + 107741184);    //       4,096
    float*  pool2 = (float*) (ws + 107745280);    //       8,192
    float*  scsh1 = (float*) (ws + 107753472);    //       1,024
    float*  scsh2 = (float*) (ws + 107754496);    //       1,024

    hipMemsetAsync(pool1, 0, 4096, stream);
    hipMemsetAsync(pool2, 0, 8192, stream);

    scsh_kernel<<<1, 256, 0, stream>>>(b1, bn1g, bn1b, bn1m, bn1v,
                                       b2, bn2g, bn2b, bn2m, bn2v, scsh1, scsh2);

    // ---- layer 1 ----
    xprep_kernel<<<dim3(256, 16), 256, 0, stream>>>(x, xT, pool1);
    mix_route_kernel<64><<<128, 256, 0, stream>>>(w1, pool1, fc1_w, fc1_b, wmix1);
    conv_mfma12_kernel<64, true><<<512, 1024, 0, stream>>>(
        xT, wmix1, scsh1, nullptr, hT);

    // ---- layer 2 ----
    pool2h_kernel<<<dim3(16, 32), 256, 0, stream>>>(hT, pool2);
    mix_route_kernel<128><<<128, 256, 0, stream>>>(w2, pool2, fc2_w, fc2_b, wmix2);
    conv_mfma12_kernel<128, false><<<512, 1024, 0, stream>>>(
        hT, wmix2, scsh2, out, nullptr);
}

// Round 15
// 204.746 us; speedup vs baseline: 1.0058x; 1.0058x over previous
//
#include <hip/hip_runtime.h>
#include <math.h>

#define BN_EPS 1e-5f

typedef short bf16x8 __attribute__((ext_vector_type(8)));
typedef float f32x4 __attribute__((ext_vector_type(4)));
typedef float f32x16 __attribute__((ext_vector_type(16)));
typedef unsigned short ushort8v __attribute__((ext_vector_type(8)));
typedef unsigned int uint;
typedef unsigned short ushort;

__device__ inline ushort f2bf(float f) {           // RNE float->bf16
    uint u = __float_as_uint(f);
    uint r = u + 0x7FFFu + ((u >> 16) & 1u);
    return (ushort)(r >> 16);
}
__device__ inline float bf2f(ushort u) { return __uint_as_float(((uint)u) << 16); }
__device__ inline uint cvtpk(float lo, float hi) { // packed 2xbf16 (RNE)
    uint r;
    asm("v_cvt_pk_bf16_f32 %0, %1, %2" : "=v"(r) : "v"(lo), "v"(hi));
    return r;
}

// ---------------------------------------------------------------------------
// Per-channel scale/shift for both BN layers: y = acc*sc + sh, then ReLU.
// ---------------------------------------------------------------------------
__global__ void scsh_kernel(const float* b1, const float* g1, const float* bb1,
                            const float* m1, const float* v1,
                            const float* b2, const float* g2, const float* bb2,
                            const float* m2, const float* v2,
                            float* scsh1, float* scsh2) {
    int t = threadIdx.x;
    if (t < 128) {
        float sc = g1[t] * rsqrtf(v1[t] + BN_EPS);
        scsh1[t] = sc;
        scsh1[128 + t] = (b1[t] - m1[t]) * sc + bb1[t];
    } else {
        int c = t - 128;
        float sc = g2[c] * rsqrtf(v2[c] + BN_EPS);
        scsh2[c] = sc;
        scsh2[128 + c] = (b2[c] - m2[c]) * sc + bb2[c];
    }
}

// ---------------------------------------------------------------------------
// x fp32 NCHW [16][64][128][128] -> xT bf16 16ci-planar [b][h][cc4][w][16]
// + fused pool partial sums (atomicAdd raw sums into pooled1).
// ---------------------------------------------------------------------------
__global__ void xprep_kernel(const float* __restrict__ x, ushort* __restrict__ xT,
                             float* __restrict__ pooled1) {
    __shared__ float t[64][65];
    const int b = blockIdx.y;
    const int p0 = blockIdx.x * 64;
    const int tid = threadIdx.x;
#pragma unroll
    for (int it = 0; it < 16; ++it) {
        const int idx = it * 256 + tid;
        const int ci = idx >> 6, p = idx & 63;
        t[ci][p] = x[((size_t)b * 64 + ci) * 16384 + p0 + p];
    }
    __syncthreads();
    const int h = p0 >> 7;
#pragma unroll
    for (int it = 0; it < 2; ++it) {
        const int p = it * 32 + (tid >> 3);
        const int w = (p0 & 127) + p;
        const int c0 = (tid & 7) * 8;
        const int cc = c0 >> 4;
        ushort8v u;
#pragma unroll
        for (int j = 0; j < 8; ++j) u[j] = f2bf(t[c0 + j][p]);
        *(ushort8v*)&xT[(((size_t)(b * 128 + h) * 4 + cc) * 128 + w) * 16 + (c0 & 15)] = u;
    }
    if (tid < 64) {
        float s = 0.f;
#pragma unroll 8
        for (int p = 0; p < 64; ++p) s += t[tid][p];
        atomicAdd(&pooled1[b * 64 + tid], s);
    }
}

// ---------------------------------------------------------------------------
// Pool hT (bf16 16ci-planar [b][h][cc8][w][16]) -> pooled2 raw sums (atomic).
// ---------------------------------------------------------------------------
__global__ void pool2h_kernel(const ushort* __restrict__ hT, float* __restrict__ pooled2) {
    const int b = blockIdx.x, slab = blockIdx.y;
    const int tid = threadIdx.x;                  // 256
    const int cc = tid >> 5, o = (tid >> 4) & 1, wb = tid & 15;
    float a[8] = {0.f, 0.f, 0.f, 0.f, 0.f, 0.f, 0.f, 0.f};
    for (int r = 0; r < 4; ++r) {
        const int h = slab * 4 + r;
        const ushort* base = hT + ((size_t)(b * 128 + h) * 8 + cc) * 2048 + o * 8;
#pragma unroll
        for (int k = 0; k < 8; ++k) {
            const ushort8v u = *(const ushort8v*)(base + (wb + k * 16) * 16);
#pragma unroll
            for (int j = 0; j < 8; ++j) a[j] += bf2f(u[j]);
        }
    }
    __shared__ float sp[16][8][17];
    const int grp0 = cc * 2 + o;
#pragma unroll
    for (int j = 0; j < 8; ++j) sp[grp0][j][wb] = a[j];
    __syncthreads();
    if (tid < 128) {
        const int grp = tid >> 3, j = tid & 7;
        float s = 0.f;
#pragma unroll
        for (int k = 0; k < 16; ++k) s += sp[grp][j][k];
        const int c = (grp >> 1) * 16 + (grp & 1) * 8 + j;
        atomicAdd(&pooled2[b * 128 + c], s);
    }
}

// ---------------------------------------------------------------------------
// Routing (from raw pooled sums) + expert mix, writing wmix as the conv
// kernel's LDS weight image: per (b,cc16): 2304 granules of 16B,
// granule = tap*256 + oct*128 + co  (LINEAR), elems = 8 ci.
// ---------------------------------------------------------------------------
template <int CIN>
__global__ void mix_route_kernel(const float* __restrict__ w, const float* __restrict__ pooled,
                                 const float* __restrict__ fcw, const float* __restrict__ fcb,
                                 ushort* __restrict__ wmix) {
    constexpr int NCC = CIN / 16;
    __shared__ float rwl[48];
    const int tid = threadIdx.x;
    if (tid < 48) {
        const int bb = tid / 3, e = tid % 3;
        float d = 0.f;
        for (int c = 0; c < CIN; ++c) d += pooled[bb * CIN + c] * fcw[e * CIN + c];
        const float s = fcb[e] + d * (1.f / 16384.f);
        rwl[tid] = 1.f / (1.f + expf(-s));
    }
    __syncthreads();
    const int co = blockIdx.x;           // 0..127
    for (int b = 0; b < 16; ++b) {
        const float r0 = rwl[b * 3 + 0], r1 = rwl[b * 3 + 1], r2 = rwl[b * 3 + 2];
        for (int idx = tid; idx < CIN * 9; idx += 256) {
            const int ci = idx & (CIN - 1);
            const int tap = idx / CIN;
            const size_t off = ((size_t)co * CIN + ci) * 9 + tap;
            const float m = r0 * w[off]
                          + r1 * w[off + (size_t)128 * CIN * 9]
                          + r2 * w[off + (size_t)2 * 128 * CIN * 9];
            const int cc = ci >> 4, o = (ci >> 3) & 1, e = ci & 7;
            const size_t dst = ((size_t)(b * NCC + cc) * 2304
                             + tap * 256 + o * 128 + co) * 8 + e;
            wmix[dst] = f2bf(m);
        }
    }
}

// ---------------------------------------------------------------------------
// MFMA implicit-GEMM conv3x3(pad1) + fused bias/BN/ReLU. v15 (= v13 + T3):
//  - v13 base: 16 waves (4/SIMD), wave tile 64co x (2rows x 32px), rolling
//    B-frags, linear LDS layouts, base+imm reads, I+W double-buffer
//  - PHASE-SPLIT SCHEDULE (T3, the m201 8-phase template at dy granularity):
//    per chunk, 3 phases (dy=0,1,2; 12 MFMAs each):
//      {rb ds_reads + 1-2 stage gllds} -> s_barrier -> lgkmcnt(0)+sched_barrier
//      -> setprio(1) [af reads + 12 MFMA] setprio(0) -> s_barrier
//    Stage loads span >=2 phases before the per-chunk vmcnt(0) (free wait);
//    dual barriers per phase create the wave role-split that makes setprio
//    and in-flight loads pay (catalog: T4/T5 null on 2-phase, +20-40% on T3).
// ---------------------------------------------------------------------------
template <int CIN, bool TO_BF16>
__global__ __launch_bounds__(1024, 4)
void conv_mfma13_kernel(const ushort* __restrict__ xT, const ushort* __restrict__ wmix,
                        const float* __restrict__ scsh,
                        float* __restrict__ outf, ushort* __restrict__ outh) {
    constexpr int NCC = CIN / 16;
    constexpr int IBUF = 24960;          // 6 rows * 260 granules * 16B
    constexpr int WOFF = 2 * IBUF;       // 49920
    constexpr int WBUF = 36864;          // 2304 granules * 16B
    __shared__ __align__(16) char smem[123648];

    const int L = ((blockIdx.x & 7) << 6) | (blockIdx.x >> 3);  // 64 per XCD
    const int b = L >> 5;
    const int rt = L & 31;               // output rows rt*4 .. rt*4+3

    const int tid = threadIdx.x;
    const int lane = tid & 63, wid = tid >> 6;   // 16 waves
    const int wm = wid >> 3;                     // 0..1 co-half
    const int rp = (wid >> 2) & 1;               // 0..1 row-pair
    const int cb = wid & 3;                      // 0..3 col-block (32 px)
    const int l31 = lane & 31, lhi = lane >> 5;

    f32x16 acc[2][2];                            // [mf][nf=row-in-pair]
#pragma unroll
    for (int i = 0; i < 2; ++i)
#pragma unroll
        for (int j = 0; j < 2; ++j)
#pragma unroll
            for (int r = 0; r < 16; ++r) acc[i][j][r] = 0.f;

    const ushort* inb = xT + (size_t)b * 128 * NCC * 2048;
    const ushort* wmb = wmix + (size_t)b * NCC * 18432;

    // ---- hoisted staging state (v13 slot map) ----
    const int ihalf = wid & 1, ioct = (wid >> 1) & 1, ir0 = (wid & 15) >> 2;
    const int iv = (ihalf * 64 + lane) * 16 + ioct * 8;   // ushort off in (row,cc)
    const int idst0 = (ir0 * 260 + ioct * 130 + 1 + ihalf * 64) * 16;
    const int hg0 = rt * 4 - 1 + ir0;
    const bool ok0 = (unsigned)hg0 < 128u;
    const bool ok4 = (wid < 8) && ((unsigned)(hg0 + 4) < 128u);
    const int wo0 = wid * 512 + lane * 8;                 // ushort, + u*8192
    const int wd0 = wid * 1024 + lane * 16;               // byte,   + u*16384

    // stage split: A = {I#1, W u=0}; B = {I#2, W u=1, (wid<4) W u=2}
    auto stageA = [&](char* dI, char* dW, int cc) {
        const size_t ccI = (size_t)cc * 2048;
        if (ok0) {
            const ushort* src = inb + (size_t)hg0 * (NCC * 2048) + ccI + iv;
            __builtin_amdgcn_global_load_lds(
                (const __attribute__((address_space(1))) void*)src,
                (__attribute__((address_space(3))) void*)(dI + idst0), 16, 0, 0);
        }
        const ushort* ws = wmb + (size_t)cc * 18432;
        __builtin_amdgcn_global_load_lds(
            (const __attribute__((address_space(1))) void*)(ws + wo0),
            (__attribute__((address_space(3))) void*)(dW + wd0), 16, 0, 0);
    };
    auto stageB = [&](char* dI, char* dW, int cc) {
        const size_t ccI = (size_t)cc * 2048;
        if (ok4) {
            const ushort* src = inb + (size_t)(hg0 + 4) * (NCC * 2048) + ccI + iv;
            __builtin_amdgcn_global_load_lds(
                (const __attribute__((address_space(1))) void*)src,
                (__attribute__((address_space(3))) void*)(dI + idst0 + 4 * 4160), 16, 0, 0);
        }
        const ushort* ws = wmb + (size_t)cc * 18432;
        __builtin_amdgcn_global_load_lds(
            (const __attribute__((address_space(1))) void*)(ws + wo0 + 8192),
            (__attribute__((address_space(3))) void*)(dW + wd0 + 16384), 16, 0, 0);
        if (wid < 4) {
            __builtin_amdgcn_global_load_lds(
                (const __attribute__((address_space(1))) void*)(ws + wo0 + 16384),
                (__attribute__((address_space(3))) void*)(dW + wd0 + 32768), 16, 0, 0);
        }
    };

    // per-lane read bases (halo at colp 0 => no +1)
    const int ibase = (rp * 2 * 260 + lhi * 130 + cb * 32 + l31) * 16;
    const int wbase = (lhi * 128 + wm * 64 + l31) * 16;
    const char* pI0 = smem + ibase;
    const char* pI1 = smem + IBUF + ibase;
    const char* pW0 = smem + WOFF + wbase;
    const char* pW1 = smem + WOFF + WBUF + wbase;

    // 12 MFMAs of one dy (af reads inline; compiler emits fine lgkm waits)
    auto mfma_dy = [&](const char* pW, int dy, const bf16x8* rlo, const bf16x8* rhi) {
#pragma unroll
        for (int dx = 0; dx < 3; ++dx) {
            const int tap = dy * 3 + dx;
            const bf16x8 af0 = *(const bf16x8*)(pW + (tap * 256) * 16);
            const bf16x8 af1 = *(const bf16x8*)(pW + (tap * 256 + 32) * 16);
            acc[0][0] = __builtin_amdgcn_mfma_f32_32x32x16_bf16(af0, rlo[dx], acc[0][0], 0, 0, 0);
            acc[1][0] = __builtin_amdgcn_mfma_f32_32x32x16_bf16(af1, rlo[dx], acc[1][0], 0, 0, 0);
            acc[0][1] = __builtin_amdgcn_mfma_f32_32x32x16_bf16(af0, rhi[dx], acc[0][1], 0, 0, 0);
            acc[1][1] = __builtin_amdgcn_mfma_f32_32x32x16_bf16(af1, rhi[dx], acc[1][1], 0, 0, 0);
        }
    };

    // one chunk = 3 phases (dy); stage for next chunk spread over P0/P1
    auto chunk3 = [&](const char* pI, const char* pW, char* dIn, char* dWn,
                      int ccn, bool doStage) {
        bf16x8 rb0[3], rb1[3], rb2[3];
        // ---- P0: rows 0,1 + stageA ----
#pragma unroll
        for (int dx = 0; dx < 3; ++dx) {
            rb0[dx] = *(const bf16x8*)(pI + (0 * 260 + dx) * 16);
            rb1[dx] = *(const bf16x8*)(pI + (1 * 260 + dx) * 16);
        }
        if (doStage) stageA(dIn, dWn, ccn);
        __builtin_amdgcn_s_barrier();
        asm volatile("s_waitcnt lgkmcnt(0)" ::: "memory");
        __builtin_amdgcn_sched_barrier(0);
        __builtin_amdgcn_s_setprio(1);
        mfma_dy(pW, 0, rb0, rb1);
        __builtin_amdgcn_s_setprio(0);
        __builtin_amdgcn_s_barrier();
        // ---- P1: row 2 + stageB ----
#pragma unroll
        for (int dx = 0; dx < 3; ++dx)
            rb2[dx] = *(const bf16x8*)(pI + (2 * 260 + dx) * 16);
        if (doStage) stageB(dIn, dWn, ccn);
        __builtin_amdgcn_s_barrier();
        asm volatile("s_waitcnt lgkmcnt(0)" ::: "memory");
        __builtin_amdgcn_sched_barrier(0);
        __builtin_amdgcn_s_setprio(1);
        mfma_dy(pW, 1, rb1, rb2);
        __builtin_amdgcn_s_setprio(0);
        __builtin_amdgcn_s_barrier();
        // ---- P2: row 3 ----
#pragma unroll
        for (int dx = 0; dx < 3; ++dx)
            rb0[dx] = *(const bf16x8*)(pI + (3 * 260 + dx) * 16);
        __builtin_amdgcn_s_barrier();
        asm volatile("s_waitcnt lgkmcnt(0)" ::: "memory");
        __builtin_amdgcn_sched_barrier(0);
        __builtin_amdgcn_s_setprio(1);
        mfma_dy(pW, 2, rb2, rb0);
        __builtin_amdgcn_s_setprio(0);
        if (doStage) asm volatile("s_waitcnt vmcnt(0)" ::: "memory");  // issued >=2 phases ago
        __builtin_amdgcn_s_barrier();   // next chunk's buffers now valid for all waves
    };

    // ---- one-time zeroing: halo cols (colp 0,129 per row/oct), both bufs ----
    if (tid < 48) {
        const int bi = tid >= 24, idx = tid - bi * 24;
        const int r = idx >> 2, j = idx & 3;
        const int g = r * 260 + (j >> 1) * 130 + (j & 1) * 129;
        *(f32x4*)(smem + bi * IBUF + g * 16) = f32x4{0.f, 0.f, 0.f, 0.f};
    }
    if (rt == 0 || rt == 31) {           // OOB image rows (r=0 or r=5)
        const int r = (rt == 0) ? 0 : 5;
        if (tid < 520) {
            const int bi = tid >= 260, gr = tid - bi * 260;
            *(f32x4*)(smem + bi * IBUF + (r * 260 + gr) * 16) = f32x4{0.f, 0.f, 0.f, 0.f};
        }
    }

    stageA(smem, smem + WOFF, 0);
    stageB(smem, smem + WOFF, 0);
    asm volatile("s_waitcnt vmcnt(0) lgkmcnt(0)" ::: "memory");
    __builtin_amdgcn_s_barrier();        // stage(0) + zeroes visible

    for (int cc = 0; cc < NCC; cc += 2) {
        chunk3(pI0, pW0, smem + IBUF, smem + WOFF + WBUF, cc + 1, true);
        chunk3(pI1, pW1, smem, smem + WOFF, cc + 2, cc + 2 < NCC);
    }
    __builtin_amdgcn_sched_barrier(0);

    // ---- epilogue: y = relu(acc*sc + sh) ----
    if constexpr (!TO_BF16) {
        // fp32 NCHW direct: each (mf,q,s,nf) = 32 consecutive floats of a row
#pragma unroll
        for (int mf = 0; mf < 2; ++mf) {
            const int cob = wm * 64 + mf * 32 + 4 * lhi;
            f32x4 sc[4], sh[4];
#pragma unroll
            for (int q = 0; q < 4; ++q) {
                sc[q] = *(const f32x4*)&scsh[cob + 8 * q];
                sh[q] = *(const f32x4*)&scsh[128 + cob + 8 * q];
            }
#pragma unroll
            for (int nf = 0; nf < 2; ++nf) {
                const size_t pbase = (size_t)(rt * 4 + rp * 2 + nf) * 128 + cb * 32 + l31;
#pragma unroll
                for (int q = 0; q < 4; ++q)
#pragma unroll
                    for (int s = 0; s < 4; ++s) {
                        float y = fmaf(acc[mf][nf][q * 4 + s], sc[q][s], sh[q][s]);
                        y = y > 0.f ? y : 0.f;
                        outf[((size_t)(b * 128 + cob + 8 * q + s)) * 16384 + pbase] = y;
                    }
            }
        }
    } else {
        // bf16 16ci-planar hT via padded-LDS transpose, 2 passes of 2 rows
        ushort* sf = (ushort*)smem;                      // [256 px][136]
#pragma unroll
        for (int p = 0; p < 2; ++p) {
            if (rp == p) {
#pragma unroll
                for (int mf = 0; mf < 2; ++mf)
#pragma unroll
                    for (int q = 0; q < 4; ++q) {
                        const int co4 = wm * 64 + mf * 32 + 8 * q + 4 * lhi;
                        const f32x4 sc = *(const f32x4*)&scsh[co4];
                        const f32x4 sh = *(const f32x4*)&scsh[128 + co4];
#pragma unroll
                        for (int nf = 0; nf < 2; ++nf) {
                            const int px = nf * 128 + cb * 32 + l31;
                            float v[4];
#pragma unroll
                            for (int s = 0; s < 4; ++s) {
                                float y = fmaf(acc[mf][nf][q * 4 + s], sc[s], sh[s]);
                                v[s] = y > 0.f ? y : 0.f;
                            }
                            uint2 pk;
                            pk.x = cvtpk(v[0], v[1]);
                            pk.y = cvtpk(v[2], v[3]);
                            *(uint2*)&sf[px * 136 + co4] = pk;
                        }
                    }
            }
            __syncthreads();
#pragma unroll
            for (int it = 0; it < 2; ++it) {
                const int id = it * 1024 + tid;          // [lr2][cc8][w128]
                const int lr = id >> 10, cc = (id >> 7) & 7, w = id & 127;
                const uint4 v0 = *(const uint4*)&sf[(lr * 128 + w) * 136 + cc * 16];
                const uint4 v1 = *(const uint4*)&sf[(lr * 128 + w) * 136 + cc * 16 + 8];
                ushort* dst = outh + (((size_t)(b * 128 + rt * 4 + 2 * p + lr)) * 8 + cc) * 2048 + w * 16;
                *(uint4*)dst = v0;
                *(uint4*)(dst + 8) = v1;
            }
            if (p == 0) __syncthreads();
        }
    }
}

// ---------------------------------------------------------------------------
extern "C" void kernel_launch(void* const* d_in, const int* in_sizes, int n_in,
                              void* d_out, int out_size, void* d_ws, size_t ws_size,
                              hipStream_t stream) {
    const float* x     = (const float*)d_in[0];
    const float* w1    = (const float*)d_in[1];
    const float* b1    = (const float*)d_in[2];
    const float* fc1_w = (const float*)d_in[3];
    const float* fc1_b = (const float*)d_in[4];
    const float* bn1g  = (const float*)d_in[5];
    const float* bn1b  = (const float*)d_in[6];
    const float* bn1m  = (const float*)d_in[7];
    const float* bn1v  = (const float*)d_in[8];
    const float* w2    = (const float*)d_in[9];
    const float* b2    = (const float*)d_in[10];
    const float* fc2_w = (const float*)d_in[11];
    const float* fc2_b = (const float*)d_in[12];
    const float* bn2g  = (const float*)d_in[13];
    const float* bn2b  = (const float*)d_in[14];
    const float* bn2m  = (const float*)d_in[15];
    const float* bn2v  = (const float*)d_in[16];

    float* out = (float*)d_out;
    char* ws = (char*)d_ws;

    // workspace layout (bytes)
    ushort* hT    = (ushort*)(ws + 0);            //  67,108,864
    ushort* xT    = (ushort*)(ws + 67108864);     //  33,554,432
    ushort* wmix1 = (ushort*)(ws + 100663296);    //   2,359,296
    ushort* wmix2 = (ushort*)(ws + 103022592);    //   4,718,592
    float*  pool1 = (float*) (ws + 107741184);    //       4,096
    float*  pool2 = (float*) (ws + 107745280);    //       8,192
    float*  scsh1 = (float*) (ws + 107753472);    //       1,024
    float*  scsh2 = (float*) (ws + 107754496);    //       1,024

    hipMemsetAsync(pool1, 0, 4096, stream);
    hipMemsetAsync(pool2, 0, 8192, stream);

    scsh_kernel<<<1, 256, 0, stream>>>(b1, bn1g, bn1b, bn1m, bn1v,
                                       b2, bn2g, bn2b, bn2m, bn2v, scsh1, scsh2);

    // ---- layer 1 ----
    xprep_kernel<<<dim3(256, 16), 256, 0, stream>>>(x, xT, pool1);
    mix_route_kernel<64><<<128, 256, 0, stream>>>(w1, pool1, fc1_w, fc1_b, wmix1);
    conv_mfma13_kernel<64, true><<<512, 1024, 0, stream>>>(
        xT, wmix1, scsh1, nullptr, hT);

    // ---- layer 2 ----
    pool2h_kernel<<<dim3(16, 32), 256, 0, stream>>>(hT, pool2);
    mix_route_kernel<128><<<128, 256, 0, stream>>>(w2, pool2, fc2_w, fc2_b, wmix2);
    conv_mfma13_kernel<128, false><<<512, 1024, 0, stream>>>(
        hT, wmix2, scsh2, out, nullptr);
}

// Round 16
// 200.023 us; speedup vs baseline: 1.0295x; 1.0236x over previous
//
#include <hip/hip_runtime.h>
#include <math.h>

#define BN_EPS 1e-5f

typedef short bf16x8 __attribute__((ext_vector_type(8)));
typedef float f32x4 __attribute__((ext_vector_type(4)));
typedef float f32x16 __attribute__((ext_vector_type(16)));
typedef unsigned short ushort8v __attribute__((ext_vector_type(8)));
typedef unsigned int uint;
typedef unsigned short ushort;

__device__ inline ushort f2bf(float f) {           // RNE float->bf16
    uint u = __float_as_uint(f);
    uint r = u + 0x7FFFu + ((u >> 16) & 1u);
    return (ushort)(r >> 16);
}
__device__ inline float bf2f(ushort u) { return __uint_as_float(((uint)u) << 16); }
__device__ inline uint cvtpk(float lo, float hi) { // packed 2xbf16 (RNE)
    uint r;
    asm("v_cvt_pk_bf16_f32 %0, %1, %2" : "=v"(r) : "v"(lo), "v"(hi));
    return r;
}

// ---------------------------------------------------------------------------
// Per-channel scale/shift for both BN layers: y = acc*sc + sh, then ReLU.
// ---------------------------------------------------------------------------
__global__ void scsh_kernel(const float* b1, const float* g1, const float* bb1,
                            const float* m1, const float* v1,
                            const float* b2, const float* g2, const float* bb2,
                            const float* m2, const float* v2,
                            float* scsh1, float* scsh2) {
    int t = threadIdx.x;
    if (t < 128) {
        float sc = g1[t] * rsqrtf(v1[t] + BN_EPS);
        scsh1[t] = sc;
        scsh1[128 + t] = (b1[t] - m1[t]) * sc + bb1[t];
    } else {
        int c = t - 128;
        float sc = g2[c] * rsqrtf(v2[c] + BN_EPS);
        scsh2[c] = sc;
        scsh2[128 + c] = (b2[c] - m2[c]) * sc + bb2[c];
    }
}

// ---------------------------------------------------------------------------
// x fp32 NCHW [16][64][128][128] -> xT bf16 16ci-planar [b][h][cc4][w][16]
// + fused pool partial sums (atomicAdd raw sums into pooled1).
// ---------------------------------------------------------------------------
__global__ void xprep_kernel(const float* __restrict__ x, ushort* __restrict__ xT,
                             float* __restrict__ pooled1) {
    __shared__ float t[64][65];
    const int b = blockIdx.y;
    const int p0 = blockIdx.x * 64;
    const int tid = threadIdx.x;
#pragma unroll
    for (int it = 0; it < 16; ++it) {
        const int idx = it * 256 + tid;
        const int ci = idx >> 6, p = idx & 63;
        t[ci][p] = x[((size_t)b * 64 + ci) * 16384 + p0 + p];
    }
    __syncthreads();
    const int h = p0 >> 7;
#pragma unroll
    for (int it = 0; it < 2; ++it) {
        const int p = it * 32 + (tid >> 3);
        const int w = (p0 & 127) + p;
        const int c0 = (tid & 7) * 8;
        const int cc = c0 >> 4;
        ushort8v u;
#pragma unroll
        for (int j = 0; j < 8; ++j) u[j] = f2bf(t[c0 + j][p]);
        *(ushort8v*)&xT[(((size_t)(b * 128 + h) * 4 + cc) * 128 + w) * 16 + (c0 & 15)] = u;
    }
    if (tid < 64) {
        float s = 0.f;
#pragma unroll 8
        for (int p = 0; p < 64; ++p) s += t[tid][p];
        atomicAdd(&pooled1[b * 64 + tid], s);
    }
}

// ---------------------------------------------------------------------------
// Pool hT (bf16 16ci-planar [b][h][cc8][w][16]) -> pooled2 raw sums (atomic).
// ---------------------------------------------------------------------------
__global__ void pool2h_kernel(const ushort* __restrict__ hT, float* __restrict__ pooled2) {
    const int b = blockIdx.x, slab = blockIdx.y;
    const int tid = threadIdx.x;                  // 256
    const int cc = tid >> 5, o = (tid >> 4) & 1, wb = tid & 15;
    float a[8] = {0.f, 0.f, 0.f, 0.f, 0.f, 0.f, 0.f, 0.f};
    for (int r = 0; r < 4; ++r) {
        const int h = slab * 4 + r;
        const ushort* base = hT + ((size_t)(b * 128 + h) * 8 + cc) * 2048 + o * 8;
#pragma unroll
        for (int k = 0; k < 8; ++k) {
            const ushort8v u = *(const ushort8v*)(base + (wb + k * 16) * 16);
#pragma unroll
            for (int j = 0; j < 8; ++j) a[j] += bf2f(u[j]);
        }
    }
    __shared__ float sp[16][8][17];
    const int grp0 = cc * 2 + o;
#pragma unroll
    for (int j = 0; j < 8; ++j) sp[grp0][j][wb] = a[j];
    __syncthreads();
    if (tid < 128) {
        const int grp = tid >> 3, j = tid & 7;
        float s = 0.f;
#pragma unroll
        for (int k = 0; k < 16; ++k) s += sp[grp][j][k];
        const int c = (grp >> 1) * 16 + (grp & 1) * 8 + j;
        atomicAdd(&pooled2[b * 128 + c], s);
    }
}

// ---------------------------------------------------------------------------
// Routing (from raw pooled sums) + expert mix, writing wmix as the conv
// kernel's LDS weight image: per (b,cc16): 2304 granules of 16B,
// granule = tap*256 + oct*128 + co  (LINEAR), elems = 8 ci.
// ---------------------------------------------------------------------------
template <int CIN>
__global__ void mix_route_kernel(const float* __restrict__ w, const float* __restrict__ pooled,
                                 const float* __restrict__ fcw, const float* __restrict__ fcb,
                                 ushort* __restrict__ wmix) {
    constexpr int NCC = CIN / 16;
    __shared__ float rwl[48];
    const int tid = threadIdx.x;
    if (tid < 48) {
        const int bb = tid / 3, e = tid % 3;
        float d = 0.f;
        for (int c = 0; c < CIN; ++c) d += pooled[bb * CIN + c] * fcw[e * CIN + c];
        const float s = fcb[e] + d * (1.f / 16384.f);
        rwl[tid] = 1.f / (1.f + expf(-s));
    }
    __syncthreads();
    const int co = blockIdx.x;           // 0..127
    for (int b = 0; b < 16; ++b) {
        const float r0 = rwl[b * 3 + 0], r1 = rwl[b * 3 + 1], r2 = rwl[b * 3 + 2];
        for (int idx = tid; idx < CIN * 9; idx += 256) {
            const int ci = idx & (CIN - 1);
            const int tap = idx / CIN;
            const size_t off = ((size_t)co * CIN + ci) * 9 + tap;
            const float m = r0 * w[off]
                          + r1 * w[off + (size_t)128 * CIN * 9]
                          + r2 * w[off + (size_t)2 * 128 * CIN * 9];
            const int cc = ci >> 4, o = (ci >> 3) & 1, e = ci & 7;
            const size_t dst = ((size_t)(b * NCC + cc) * 2304
                             + tap * 256 + o * 128 + co) * 8 + e;
            wmix[dst] = f2bf(m);
        }
    }
}

// ---------------------------------------------------------------------------
// MFMA implicit-GEMM conv3x3(pad1) + fused bias/BN/ReLU. v16:
//  - 8 waves (512 thr), block tile 128co x 512px (4 rows); wave tile
//    64co x (2 rows x 64 px) = 2mf x 2row x 2colf of 32x32x16, acc 128 AGPR
//  - 4-way A reuse: each af read feeds 2rows x 2colf = 4 MFMAs; dy-rolling
//    B rows: 42 LDS reads per 72 MFMAs per chunk (0.58KB/MFMA, was 0.83)
//    -> per-CU LDS read traffic 7.9MB -> 5.4MB: MFMA becomes binding pipe
//  - linear LDS layouts ([oct][colp] / [tap][oct][co]), base+imm reads,
//    I+W double-buffer, v10's proven 2-barrier schedule
// ---------------------------------------------------------------------------
template <int CIN, bool TO_BF16>
__device__ __forceinline__
void conv_core(const ushort* __restrict__ xT, const ushort* __restrict__ wmix,
               const float* __restrict__ scsh,
               float* __restrict__ outf, ushort* __restrict__ outh) {
    constexpr int NCC = CIN / 16;
    constexpr int IBUF = 24960;          // 6 rows * 260 granules * 16B
    constexpr int WOFF = 2 * IBUF;       // 49920
    constexpr int WBUF = 36864;          // 2304 granules * 16B
    __shared__ __align__(16) char smem[123648];

    const int L = ((blockIdx.x & 7) << 6) | (blockIdx.x >> 3);  // 64 per XCD
    const int b = L >> 5;
    const int rt = L & 31;               // output rows rt*4 .. rt*4+3

    const int tid = threadIdx.x;
    const int lane = tid & 63, wid = tid >> 6;   // 8 waves
    const int wm = wid >> 2;                     // 0..1 co-half
    const int rp = (wid >> 1) & 1;               // 0..1 row-pair
    const int cb = wid & 1;                      // 0..1 col-block (64 px)
    const int l31 = lane & 31, lhi = lane >> 5;

    f32x16 acc[2][2][2];                         // [mf][rowl][cf]
#pragma unroll
    for (int i = 0; i < 2; ++i)
#pragma unroll
        for (int j = 0; j < 2; ++j)
#pragma unroll
            for (int k = 0; k < 2; ++k)
#pragma unroll
                for (int r = 0; r < 16; ++r) acc[i][j][k][r] = 0.f;

    const ushort* inb = xT + (size_t)b * 128 * NCC * 2048;
    const ushort* wmb = wmix + (size_t)b * NCC * 18432;

    // ---- hoisted staging state (8-wave slot map, v10) ----
    // I: 24 slots; slot = wid + u*8 (u<3): r=(wid>>2)+2u, oct=(wid>>1)&1, half=wid&1
    const int ihalf = wid & 1, ioct = (wid >> 1) & 1, ir0 = wid >> 2;
    const int iv = (ihalf * 64 + lane) * 16 + ioct * 8;   // ushort off in (row,cc)
    const int idst0 = (ir0 * 260 + ioct * 130 + 1 + ihalf * 64) * 16;  // + u*8320
    const int hg0 = rt * 4 - 1 + ir0;                     // + 2u
    // W: 36 slots; k = wid*4+u (u<4) + extra k=32+wid for wid<4
    const int wo0 = wid * 2048 + lane * 8;                // ushort, + u*512
    const int wd0 = wid * 4096 + lane * 16;               // byte,   + u*1024
    const int weo = 16384 + wid * 512 + lane * 8;
    const int wed = (32 + wid) * 1024 + lane * 16;

    auto stage = [&](char* dI, char* dW, int cc) {
        const size_t ccI = (size_t)cc * 2048;
#pragma unroll
        for (int u = 0; u < 3; ++u) {
            const int hg = hg0 + 2 * u;
            if ((unsigned)hg < 128u) {
                const ushort* src = inb + (size_t)hg * (NCC * 2048) + ccI + iv;
                __builtin_amdgcn_global_load_lds(
                    (const __attribute__((address_space(1))) void*)src,
                    (__attribute__((address_space(3))) void*)(dI + idst0 + u * 8320),
                    16, 0, 0);
            }
        }
        const ushort* ws = wmb + (size_t)cc * 18432;
#pragma unroll
        for (int u = 0; u < 4; ++u) {
            __builtin_amdgcn_global_load_lds(
                (const __attribute__((address_space(1))) void*)(ws + wo0 + u * 512),
                (__attribute__((address_space(3))) void*)(dW + wd0 + u * 1024),
                16, 0, 0);
        }
        if (wid < 4) {
            __builtin_amdgcn_global_load_lds(
                (const __attribute__((address_space(1))) void*)(ws + weo),
                (__attribute__((address_space(3))) void*)(dW + wed),
                16, 0, 0);
        }
    };

    // per-lane read bases. B: input tile row (rp*2 + dy + rowl),
    // colp = cb*64 + cf*32 + l31 + dx (halo at colp 0 => no +1).
    const int ibase = (rp * 2 * 260 + lhi * 130 + cb * 64 + l31) * 16;
    const int wbase = (lhi * 128 + wm * 64 + l31) * 16;
    const char* pI0 = smem + ibase;
    const char* pI1 = smem + IBUF + ibase;
    const char* pW0 = smem + WOFF + wbase;
    const char* pW1 = smem + WOFF + WBUF + wbase;

    auto taps = [&](const char* pI, const char* pW) {
        bf16x8 A0[3][2], A1[3][2];               // input rows rp*2+dy, rp*2+dy+1
#pragma unroll
        for (int dx = 0; dx < 3; ++dx)
#pragma unroll
            for (int cf = 0; cf < 2; ++cf) {
                A0[dx][cf] = *(const bf16x8*)(pI + ((0 * 260) + cf * 32 + dx) * 16);
                A1[dx][cf] = *(const bf16x8*)(pI + ((1 * 260) + cf * 32 + dx) * 16);
            }
#pragma unroll
        for (int dy = 0; dy < 3; ++dy) {
#pragma unroll
            for (int dx = 0; dx < 3; ++dx) {
                const int tap = dy * 3 + dx;
                const bf16x8 af0 = *(const bf16x8*)(pW + (tap * 256) * 16);
                const bf16x8 af1 = *(const bf16x8*)(pW + (tap * 256 + 32) * 16);
#pragma unroll
                for (int cf = 0; cf < 2; ++cf) {
                    acc[0][0][cf] = __builtin_amdgcn_mfma_f32_32x32x16_bf16(af0, A0[dx][cf], acc[0][0][cf], 0, 0, 0);
                    acc[1][0][cf] = __builtin_amdgcn_mfma_f32_32x32x16_bf16(af1, A0[dx][cf], acc[1][0][cf], 0, 0, 0);
                    acc[0][1][cf] = __builtin_amdgcn_mfma_f32_32x32x16_bf16(af0, A1[dx][cf], acc[0][1][cf], 0, 0, 0);
                    acc[1][1][cf] = __builtin_amdgcn_mfma_f32_32x32x16_bf16(af1, A1[dx][cf], acc[1][1][cf], 0, 0, 0);
                }
            }
            if (dy < 2) {
#pragma unroll
                for (int dx = 0; dx < 3; ++dx)
#pragma unroll
                    for (int cf = 0; cf < 2; ++cf) {
                        A0[dx][cf] = A1[dx][cf];
                        A1[dx][cf] = *(const bf16x8*)(pI + (((dy + 2) * 260) + cf * 32 + dx) * 16);
                    }
            }
        }
    };

    // ---- one-time zeroing: halo cols (colp 0,129 per row/oct), both bufs ----
    if (tid < 48) {
        const int bi = tid >= 24, idx = tid - bi * 24;
        const int r = idx >> 2, j = idx & 3;
        const int g = r * 260 + (j >> 1) * 130 + (j & 1) * 129;
        *(f32x4*)(smem + bi * IBUF + g * 16) = f32x4{0.f, 0.f, 0.f, 0.f};
    }
    if (rt == 0 || rt == 31) {           // OOB image rows (r=0 or r=5)
        const int r = (rt == 0) ? 0 : 5;
        for (int g = tid; g < 520; g += 512) {
            const int bi = g >= 260, gr = g - bi * 260;
            *(f32x4*)(smem + bi * IBUF + (r * 260 + gr) * 16) = f32x4{0.f, 0.f, 0.f, 0.f};
        }
    }

    stage(smem, smem + WOFF, 0);
    __syncthreads();                     // drains stage(0); zeroes visible

    for (int cc = 0; cc < NCC; cc += 2) {
        stage(smem + IBUF, smem + WOFF + WBUF, cc + 1);
        __builtin_amdgcn_sched_barrier(0);
        taps(pI0, pW0);
        __syncthreads();
        if (cc + 2 < NCC) stage(smem, smem + WOFF, cc + 2);
        __builtin_amdgcn_sched_barrier(0);
        taps(pI1, pW1);
        __syncthreads();
    }

    // ---- epilogue: y = relu(acc*sc + sh) ----
    if constexpr (!TO_BF16) {
        // fp32 NCHW direct: lanes 0-31 consecutive floats of a row
#pragma unroll
        for (int mf = 0; mf < 2; ++mf) {
            const int cob = wm * 64 + mf * 32 + 4 * lhi;
            f32x4 sc[4], sh[4];
#pragma unroll
            for (int q = 0; q < 4; ++q) {
                sc[q] = *(const f32x4*)&scsh[cob + 8 * q];
                sh[q] = *(const f32x4*)&scsh[128 + cob + 8 * q];
            }
#pragma unroll
            for (int rowl = 0; rowl < 2; ++rowl)
#pragma unroll
                for (int cf = 0; cf < 2; ++cf) {
                    const size_t pbase = (size_t)(rt * 4 + rp * 2 + rowl) * 128
                                       + cb * 64 + cf * 32 + l31;
#pragma unroll
                    for (int q = 0; q < 4; ++q)
#pragma unroll
                        for (int s = 0; s < 4; ++s) {
                            float y = fmaf(acc[mf][rowl][cf][q * 4 + s], sc[q][s], sh[q][s]);
                            y = y > 0.f ? y : 0.f;
                            outf[((size_t)(b * 128 + cob + 8 * q + s)) * 16384 + pbase] = y;
                        }
                }
        }
    } else {
        // bf16 16ci-planar hT via padded-LDS transpose, 2 passes of 2 rows
        ushort* sf = (ushort*)smem;                      // [256 px][136]
#pragma unroll
        for (int p = 0; p < 2; ++p) {
            if (rp == p) {
#pragma unroll
                for (int mf = 0; mf < 2; ++mf)
#pragma unroll
                    for (int q = 0; q < 4; ++q) {
                        const int co4 = wm * 64 + mf * 32 + 8 * q + 4 * lhi;
                        const f32x4 sc = *(const f32x4*)&scsh[co4];
                        const f32x4 sh = *(const f32x4*)&scsh[128 + co4];
#pragma unroll
                        for (int rowl = 0; rowl < 2; ++rowl)
#pragma unroll
                            for (int cf = 0; cf < 2; ++cf) {
                                const int px = rowl * 128 + cb * 64 + cf * 32 + l31;
                                float v[4];
#pragma unroll
                                for (int s = 0; s < 4; ++s) {
                                    float y = fmaf(acc[mf][rowl][cf][q * 4 + s], sc[s], sh[s]);
                                    v[s] = y > 0.f ? y : 0.f;
                                }
                                uint2 pk;
                                pk.x = cvtpk(v[0], v[1]);
                                pk.y = cvtpk(v[2], v[3]);
                                *(uint2*)&sf[px * 136 + co4] = pk;
                            }
                    }
            }
            __syncthreads();
#pragma unroll
            for (int it = 0; it < 4; ++it) {
                const int id = it * 512 + tid;           // [lr2][cc8][w128]
                const int lr = id >> 10, cc = (id >> 7) & 7, w = id & 127;
                const uint4 v0 = *(const uint4*)&sf[(lr * 128 + w) * 136 + cc * 16];
                const uint4 v1 = *(const uint4*)&sf[(lr * 128 + w) * 136 + cc * 16 + 8];
                ushort* dst = outh + (((size_t)(b * 128 + rt * 4 + 2 * p + lr)) * 8 + cc) * 2048 + w * 16;
                *(uint4*)dst = v0;
                *(uint4*)(dst + 8) = v1;
            }
            if (p == 0) __syncthreads();
        }
    }
}

// distinct names so the profiler separates the two layers
__global__ __launch_bounds__(512, 2)
void conv1_mfma14_kernel(const ushort* __restrict__ xT, const ushort* __restrict__ wmix,
                         const float* __restrict__ scsh, ushort* __restrict__ outh) {
    conv_core<64, true>(xT, wmix, scsh, nullptr, outh);
}
__global__ __launch_bounds__(512, 2)
void conv2_mfma14_kernel(const ushort* __restrict__ hT, const ushort* __restrict__ wmix,
                         const float* __restrict__ scsh, float* __restrict__ outf) {
    conv_core<128, false>(hT, wmix, scsh, outf, nullptr);
}

// ---------------------------------------------------------------------------
extern "C" void kernel_launch(void* const* d_in, const int* in_sizes, int n_in,
                              void* d_out, int out_size, void* d_ws, size_t ws_size,
                              hipStream_t stream) {
    const float* x     = (const float*)d_in[0];
    const float* w1    = (const float*)d_in[1];
    const float* b1    = (const float*)d_in[2];
    const float* fc1_w = (const float*)d_in[3];
    const float* fc1_b = (const float*)d_in[4];
    const float* bn1g  = (const float*)d_in[5];
    const float* bn1b  = (const float*)d_in[6];
    const float* bn1m  = (const float*)d_in[7];
    const float* bn1v  = (const float*)d_in[8];
    const float* w2    = (const float*)d_in[9];
    const float* b2    = (const float*)d_in[10];
    const float* fc2_w = (const float*)d_in[11];
    const float* fc2_b = (const float*)d_in[12];
    const float* bn2g  = (const float*)d_in[13];
    const float* bn2b  = (const float*)d_in[14];
    const float* bn2m  = (const float*)d_in[15];
    const float* bn2v  = (const float*)d_in[16];

    float* out = (float*)d_out;
    char* ws = (char*)d_ws;

    // workspace layout (bytes)
    ushort* hT    = (ushort*)(ws + 0);            //  67,108,864
    ushort* xT    = (ushort*)(ws + 67108864);     //  33,554,432
    ushort* wmix1 = (ushort*)(ws + 100663296);    //   2,359,296
    ushort* wmix2 = (ushort*)(ws + 103022592);    //   4,718,592
    float*  pool1 = (float*) (ws + 107741184);    //       4,096
    float*  pool2 = (float*) (ws + 107745280);    //       8,192
    float*  scsh1 = (float*) (ws + 107753472);    //       1,024
    float*  scsh2 = (float*) (ws + 107754496);    //       1,024

    hipMemsetAsync(pool1, 0, 4096, stream);
    hipMemsetAsync(pool2, 0, 8192, stream);

    scsh_kernel<<<1, 256, 0, stream>>>(b1, bn1g, bn1b, bn1m, bn1v,
                                       b2, bn2g, bn2b, bn2m, bn2v, scsh1, scsh2);

    // ---- layer 1 ----
    xprep_kernel<<<dim3(256, 16), 256, 0, stream>>>(x, xT, pool1);
    mix_route_kernel<64><<<128, 256, 0, stream>>>(w1, pool1, fc1_w, fc1_b, wmix1);
    conv1_mfma14_kernel<<<512, 512, 0, stream>>>(xT, wmix1, scsh1, hT);

    // ---- layer 2 ----
    pool2h_kernel<<<dim3(16, 32), 256, 0, stream>>>(hT, pool2);
    mix_route_kernel<128><<<128, 256, 0, stream>>>(w2, pool2, fc2_w, fc2_b, wmix2);
    conv2_mfma14_kernel<<<512, 512, 0, stream>>>(hT, wmix2, scsh2, out);
}